// Round 1
// baseline (1349.955 us; speedup 1.0000x reference)
//
#include <hip/hip_runtime.h>
#include <hip/hip_bf16.h>
#include <math.h>

// Problem shape (from reference): N=100000, OBS=16, FEAT=96 -> 1536 floats per
// candidate; PRED*FEAT = 2400 floats output. Memory-bound: must stream 614 MB
// of train_poses; roofline ~98 us at 6.3 TB/s achievable.

#define CAND_F 1536          // OBS*FEAT floats per candidate
#define CAND_V4 384          // float4 per candidate
#define OUT_F 2400           // PRED*FEAT floats
#define OUT_V4 600

__global__ void nn_init_ws(unsigned long long* ws) {
    *ws = 0xFFFFFFFFFFFFFFFFull;
}

// One wave (64 lanes) per candidate, grid-strided. Lane l owns float4 slots
// {j*64+l : j=0..5} of the 384-float4 candidate row -> fully coalesced 1 KB
// segments per load instruction. Query fragment lives in registers (same
// lane-mapping for every candidate).
__global__ __launch_bounds__(256) void nn_dist(
    const float* __restrict__ query,      // [1536]
    const float* __restrict__ train,      // [N, 1536]
    unsigned long long* __restrict__ ws,  // packed (dist_bits<<32 | idx) min
    int N)
{
    const int lane = threadIdx.x & 63;
    const int waveInBlock = threadIdx.x >> 6;
    const int gwave = blockIdx.x * 4 + waveInBlock;
    const int W = gridDim.x * 4;

    // Preload this lane's query fragment into registers (24 floats).
    float4 qf[6];
    const float4* q4 = (const float4*)query;
#pragma unroll
    for (int j = 0; j < 6; ++j)
        qf[j] = q4[j * 64 + lane];

    unsigned long long bestKey = 0xFFFFFFFFFFFFFFFFull;

    for (int n = gwave; n < N; n += W) {
        const float4* p = (const float4*)(train + (size_t)n * CAND_F);
        float sse = 0.0f;
#pragma unroll
        for (int j = 0; j < 6; ++j) {
            float4 t = p[j * 64 + lane];
            float dx = t.x - qf[j].x; sse = fmaf(dx, dx, sse);
            float dy = t.y - qf[j].y; sse = fmaf(dy, dy, sse);
            float dz = t.z - qf[j].z; sse = fmaf(dz, dz, sse);
            float dw = t.w - qf[j].w; sse = fmaf(dw, dw, sse);
        }
        // 64-lane butterfly reduction (wave = 64 on CDNA!)
#pragma unroll
        for (int off = 32; off > 0; off >>= 1)
            sse += __shfl_xor(sse, off, 64);
        // sse >= 0 -> float bit pattern is monotone as uint. Pack with index:
        // min key == (min dist, then min index) == argmin first-occurrence.
        unsigned long long key =
            ((unsigned long long)__float_as_uint(sse) << 32) | (unsigned int)n;
        bestKey = key < bestKey ? key : bestKey;
    }

    // Block reduction: 4 waves -> 1 atomic per block.
    __shared__ unsigned long long smin[4];
    if (lane == 0) smin[waveInBlock] = bestKey;
    __syncthreads();
    if (threadIdx.x == 0) {
        unsigned long long k = smin[0];
#pragma unroll
        for (int i = 1; i < 4; ++i)
            k = smin[i] < k ? smin[i] : k;
        atomicMin(ws, k);  // device-scope by default on CDNA
    }
}

__global__ void nn_gather(const float* __restrict__ target_vels,
                          const unsigned long long* __restrict__ ws,
                          float* __restrict__ out)
{
    const unsigned int idx = (unsigned int)(*ws & 0xFFFFFFFFull);
    const float4* src = (const float4*)(target_vels + (size_t)idx * OUT_F);
    float4* dst = (float4*)out;
    int i = blockIdx.x * blockDim.x + threadIdx.x;
    if (i < OUT_V4) dst[i] = src[i];
}

extern "C" void kernel_launch(void* const* d_in, const int* in_sizes, int n_in,
                              void* d_out, int out_size, void* d_ws, size_t ws_size,
                              hipStream_t stream) {
    const float* in_pose     = (const float*)d_in[0];
    const float* train_poses = (const float*)d_in[1];
    const float* target_vels = (const float*)d_in[2];
    float* out = (float*)d_out;
    unsigned long long* ws = (unsigned long long*)d_ws;

    const int N = in_sizes[1] / CAND_F;  // 100000

    nn_init_ws<<<1, 1, 0, stream>>>(ws);

    // 2048 blocks x 256 thr = 8192 waves, ~12 candidates/wave; saturates all
    // 256 CUs with grid-stride streaming reads.
    nn_dist<<<2048, 256, 0, stream>>>(in_pose, train_poses, ws, N);

    nn_gather<<<3, 256, 0, stream>>>(target_vels, ws, out);
}